// Round 1
// baseline (318.776 us; speedup 1.0000x reference)
//
#include <hip/hip_runtime.h>
#include <math.h>

#define SLEN 4096
#define DH 64
#define BHN 64

static constexpr float ANG = (float)(1.5707963267948966 / 4096.0); // (pi/2)/S

// ---------------- Kernel 1: partial KV aggregation over an S-chunk ----------
// part layout: [bh][ch][2][64][64] fp32  (2 = cos, sin)
__global__ __launch_bounds__(256) void kv_partial_kernel(
    const float* __restrict__ k, const float* __restrict__ v,
    float* __restrict__ part, int CH, int rowsPer)
{
    const int bx = blockIdx.x;
    const int bh = bx / CH;
    const int ch = bx % CH;
    const size_t base = (size_t)bh * SLEN * DH;

    const int t    = threadIdx.x;
    const int ts_l = t >> 6;    // 0..3 staging row
    const int d_l  = t & 63;    // staging col
    const int dg   = t >> 4;    // 0..15
    const int eg   = t & 15;    // 0..15
    const int d0   = dg * 4;
    const int e0   = eg * 4;

    __shared__ float kc[4][68], ks[4][68], vv[4][68];

    float accC[4][4] = {};
    float accS[4][4] = {};

    const int s0 = ch * rowsPer;
    for (int s = s0; s < s0 + rowsPer; s += 4) {
        __syncthreads();
        const int srow = s + ts_l;
        const float kx = k[base + (size_t)srow * DH + d_l];
        const float vx = v[base + (size_t)srow * DH + d_l];
        const float kf = (kx < 0.f) ? __expf(kx) : (kx + 1.f);
        float sn, c;
        __sincosf(ANG * (float)srow, &sn, &c);
        kc[ts_l][d_l] = kf * c;
        ks[ts_l][d_l] = kf * sn;
        vv[ts_l][d_l] = vx;
        __syncthreads();

        #pragma unroll
        for (int ts = 0; ts < 4; ++ts) {
            const float4 a  = *(const float4*)&kc[ts][d0];
            const float4 b  = *(const float4*)&ks[ts][d0];
            const float4 ve = *(const float4*)&vv[ts][e0];
            const float av[4] = {a.x, a.y, a.z, a.w};
            const float sv[4] = {b.x, b.y, b.z, b.w};
            const float ev[4] = {ve.x, ve.y, ve.z, ve.w};
            #pragma unroll
            for (int i = 0; i < 4; ++i) {
                #pragma unroll
                for (int j = 0; j < 4; ++j) {
                    accC[i][j] = fmaf(av[i], ev[j], accC[i][j]);
                    accS[i][j] = fmaf(sv[i], ev[j], accS[i][j]);
                }
            }
        }
    }

    const size_t pb = (size_t)bx * 8192; // bx == bh*CH + ch
    #pragma unroll
    for (int i = 0; i < 4; ++i) {
        float4 wc = make_float4(accC[i][0], accC[i][1], accC[i][2], accC[i][3]);
        float4 wsv = make_float4(accS[i][0], accS[i][1], accS[i][2], accS[i][3]);
        *(float4*)&part[pb + (size_t)(d0 + i) * 64 + e0]        = wc;
        *(float4*)&part[pb + 4096 + (size_t)(d0 + i) * 64 + e0] = wsv;
    }
}

// ---------------- Kernel 2: reduce chunk partials into chunk 0 --------------
__global__ __launch_bounds__(256) void kv_reduce_kernel(
    float* __restrict__ part, int CH)
{
    const int bh = blockIdx.x;
    const size_t b0 = (size_t)bh * CH * 8192;
    for (int j = threadIdx.x; j < 8192; j += 256) {
        float sum = 0.f;
        for (int ch = 0; ch < CH; ++ch)
            sum += part[b0 + (size_t)ch * 8192 + j];
        part[b0 + j] = sum;
    }
}

// ---------------- Kernel 3: out = Qc*KVc + Qs*KVs ---------------------------
__global__ __launch_bounds__(256) void out_kernel(
    const float* __restrict__ q, const float* __restrict__ kv,
    float* __restrict__ out, int CH)
{
    const int bx = blockIdx.x;
    const int bh = bx >> 6;   // 64 row-blocks per bh
    const int rb = bx & 63;
    const size_t qbase = (size_t)bh * SLEN * DH;
    const size_t kvb   = (size_t)bh * CH * 8192; // reduced kv sits at chunk 0
    const int t = threadIdx.x;

    __shared__ float kvc[64][64], kvs[64][64];
    __shared__ float qct[64][64], qst[64][64]; // [d][row^swz], transposed q

    for (int i = t; i < 4096; i += 256) {
        kvc[i >> 6][i & 63] = kv[kvb + i];
        kvs[i >> 6][i & 63] = kv[kvb + 4096 + i];
    }
    const int s0 = rb * 64;
    for (int i = t; i < 4096; i += 256) {
        const int row = i >> 6;
        const int d   = i & 63;
        const float x  = q[qbase + (size_t)(s0 + row) * DH + d];
        const float qf = (x < 0.f) ? __expf(x) : (x + 1.f);
        float sn, c;
        __sincosf(ANG * (float)(s0 + row), &sn, &c);
        const int rsw = row ^ ((d & 7) << 2); // XOR swizzle, keeps 16B groups
        qct[d][rsw] = qf * c;
        qst[d][rsw] = qf * sn;
    }
    __syncthreads();

    const int rg = t >> 4;  // 0..15 -> 4 rows each
    const int eg = t & 15;  // 0..15 -> 4 cols each
    const int r0 = rg * 4;
    const int e0 = eg * 4;
    float acc[4][4] = {};

    #pragma unroll 8
    for (int d = 0; d < 64; ++d) {
        const int rs = r0 ^ ((d & 7) << 2);
        const float4 qc4 = *(const float4*)&qct[d][rs];
        const float4 qs4 = *(const float4*)&qst[d][rs];
        const float4 bc  = *(const float4*)&kvc[d][e0];
        const float4 bs  = *(const float4*)&kvs[d][e0];
        const float qcv[4] = {qc4.x, qc4.y, qc4.z, qc4.w};
        const float qsv[4] = {qs4.x, qs4.y, qs4.z, qs4.w};
        const float bcv[4] = {bc.x, bc.y, bc.z, bc.w};
        const float bsv[4] = {bs.x, bs.y, bs.z, bs.w};
        #pragma unroll
        for (int i = 0; i < 4; ++i) {
            #pragma unroll
            for (int j = 0; j < 4; ++j) {
                acc[i][j] = fmaf(qcv[i], bcv[j], acc[i][j]);
                acc[i][j] = fmaf(qsv[i], bsv[j], acc[i][j]);
            }
        }
    }

    #pragma unroll
    for (int i = 0; i < 4; ++i) {
        const size_t o = ((size_t)bh * SLEN + (size_t)(s0 + r0 + i)) * 64 + e0;
        *(float4*)&out[o] = make_float4(acc[i][0], acc[i][1], acc[i][2], acc[i][3]);
    }
}

extern "C" void kernel_launch(void* const* d_in, const int* in_sizes, int n_in,
                              void* d_out, int out_size, void* d_ws, size_t ws_size,
                              hipStream_t stream) {
    const float* q = (const float*)d_in[0];
    const float* k = (const float*)d_in[1];
    const float* v = (const float*)d_in[2];
    float* out  = (float*)d_out;
    float* part = (float*)d_ws;

    // pick largest CH (power of 2, <=16) whose partial buffer fits ws
    int CH = 16;
    const size_t perChunk = (size_t)BHN * 8192 * sizeof(float); // 2 MB
    while (CH > 1 && (size_t)CH * perChunk > ws_size) CH >>= 1;
    const int rowsPer = SLEN / CH;

    hipLaunchKernelGGL(kv_partial_kernel, dim3(BHN * CH), dim3(256), 0, stream,
                       k, v, part, CH, rowsPer);
    if (CH > 1)
        hipLaunchKernelGGL(kv_reduce_kernel, dim3(BHN), dim3(256), 0, stream,
                           part, CH);
    hipLaunchKernelGGL(out_kernel, dim3(BHN * 64), dim3(256), 0, stream,
                       q, part, out, CH);
}

// Round 2
// 74.397 us; speedup vs baseline: 4.2848x; 4.2848x over previous
//
#include <hip/hip_runtime.h>
#include <math.h>

#define SLEN 4096
#define DH   64
#define BHN  64
#define CH   8
#define ROWSPER 512   // SLEN / CH
#define SPAD 72       // LDS row stride in shorts: multiple of 8 (16B align for b128)

typedef float  f32x4  __attribute__((ext_vector_type(4)));
typedef __bf16 bf16x8 __attribute__((ext_vector_type(8)));

static constexpr float ANG = 1.5707963267948966f / 4096.0f; // (pi/2)/S

static __device__ __forceinline__ float featf(float x) {
    return x < 0.f ? __expf(x) : x + 1.f;   // elu+1 feature map
}
static __device__ __forceinline__ void pack2(short* p, float a, float b) {
    union { __bf16 h[2]; unsigned u; } uu;
    uu.h[0] = (__bf16)a; uu.h[1] = (__bf16)b;
    *(unsigned*)p = uu.u;                    // two bf16 (adjacent s) in one b32 write
}

// ---------------- Kernel 1: partial KV aggregation (MFMA) -------------------
// part layout: [bh*CH + ch][2(cos,sin)][64 d][64 e] fp32
__global__ __launch_bounds__(256) void kv_partial(const float* __restrict__ k,
                                                  const float* __restrict__ v,
                                                  float* __restrict__ part)
{
    __shared__ short kcT[64 * SPAD];  // [d][s] bf16 bits
    __shared__ short ksT[64 * SPAD];
    __shared__ short vT [64 * SPAD];  // [e][s]

    const int bx = blockIdx.x;
    const int bh = bx >> 3, ch = bx & 7;
    const size_t base = (size_t)bh * SLEN * DH;
    const int t  = threadIdx.x;
    const int wv = t >> 6;          // wave id: owns d-panel [16wv,16wv+16)
    const int ln = t & 63;
    const int m  = ln & 15;
    const int g  = ln >> 4;

    const int d0 = (t & 15) * 4;    // staging: 4 feature cols
    const int sg = t >> 4;          // staging: row-pair index 0..15

    f32x4 aC[4] = {}; f32x4 aS[4] = {};

    for (int tile = 0; tile < 8; ++tile) {
        const int srow0 = ch * ROWSPER + tile * 64;
        __syncthreads();
        #pragma unroll
        for (int it = 0; it < 2; ++it) {
            const int sl = it * 32 + sg * 2;        // local row (even)
            const int srow = srow0 + sl;
            float sn0, c0, sn1, c1;
            __sincosf(ANG * (float)srow,       &sn0, &c0);
            __sincosf(ANG * (float)(srow + 1), &sn1, &c1);
            const f32x4 k0 = *(const f32x4*)&k[base + (size_t)srow * DH + d0];
            const f32x4 k1 = *(const f32x4*)&k[base + (size_t)(srow + 1) * DH + d0];
            const f32x4 v0 = *(const f32x4*)&v[base + (size_t)srow * DH + d0];
            const f32x4 v1 = *(const f32x4*)&v[base + (size_t)(srow + 1) * DH + d0];
            #pragma unroll
            for (int i = 0; i < 4; ++i) {
                const float kf0 = featf(k0[i]);
                const float kf1 = featf(k1[i]);
                const int rowoff = (d0 + i) * SPAD + sl;
                pack2(&kcT[rowoff], kf0 * c0,  kf1 * c1);
                pack2(&ksT[rowoff], kf0 * sn0, kf1 * sn1);
                pack2(&vT [rowoff], v0[i],     v1[i]);
            }
        }
        __syncthreads();
        #pragma unroll
        for (int b = 0; b < 2; ++b) {
            const int so = b * 32 + g * 8;   // 8 consecutive s per lane
            const bf16x8 Ac = *(const bf16x8*)&kcT[(wv * 16 + m) * SPAD + so];
            const bf16x8 As = *(const bf16x8*)&ksT[(wv * 16 + m) * SPAD + so];
            #pragma unroll
            for (int nt = 0; nt < 4; ++nt) {
                const bf16x8 Bv = *(const bf16x8*)&vT[(nt * 16 + m) * SPAD + so];
                aC[nt] = __builtin_amdgcn_mfma_f32_16x16x32_bf16(Ac, Bv, aC[nt], 0, 0, 0);
                aS[nt] = __builtin_amdgcn_mfma_f32_16x16x32_bf16(As, Bv, aS[nt], 0, 0, 0);
            }
        }
    }

    // C/D: col = lane&15, row = 4*(lane>>4)+reg  [HW-verified]
    const size_t pb = (size_t)bx * 8192;
    #pragma unroll
    for (int nt = 0; nt < 4; ++nt) {
        #pragma unroll
        for (int r = 0; r < 4; ++r) {
            const size_t rowb = (size_t)(wv * 16 + g * 4 + r) * 64 + nt * 16 + m;
            part[pb        + rowb] = aC[nt][r];
            part[pb + 4096 + rowb] = aS[nt][r];
        }
    }
}

// ---------------- Kernel 2: reduce chunks, emit bf16 KV^T -------------------
// kvT layout: [bh][2(cos,sin)][64 e][64 d] bf16
__global__ __launch_bounds__(256) void kv_reduce(const float* __restrict__ part,
                                                 short* __restrict__ kvT)
{
    const int bx = blockIdx.x;
    const int bh = bx >> 2, qd = bx & 3;   // qd: d-quarter
    const size_t pbase = (size_t)bh * CH * 8192;
    for (int i = threadIdx.x; i < 2048; i += 256) {
        const int cs = i >> 10;
        const int dl = (i >> 6) & 15;
        const int e  = i & 63;
        const int d  = qd * 16 + dl;
        const int j  = cs * 4096 + d * 64 + e;
        float s = 0.f;
        #pragma unroll
        for (int c = 0; c < CH; ++c) s += part[pbase + (size_t)c * 8192 + j];
        __bf16 hv = (__bf16)s;
        kvT[(size_t)bh * 8192 + cs * 4096 + e * 64 + d] = *(short*)&hv;
    }
}

// ---------------- Kernel 3: out = Qc*KVc + Qs*KVs (MFMA) --------------------
__global__ __launch_bounds__(256) void out_kernel(const float* __restrict__ q,
                                                  const short* __restrict__ kvT,
                                                  float* __restrict__ out)
{
    const int bx = blockIdx.x;
    const int bh = bx >> 4, chunk = bx & 15;
    const int t = threadIdx.x;
    const int wv = t >> 6, ln = t & 63, m = ln & 15, g = ln >> 4;
    const size_t qbase = (size_t)bh * SLEN * DH;
    const size_t kvb   = (size_t)bh * 8192;

    // B fragments: slot j of group g <-> d = 32b + 8g + j (same map as A below)
    bf16x8 Bc[4][2], Bs[4][2];
    #pragma unroll
    for (int nt = 0; nt < 4; ++nt)
        #pragma unroll
        for (int b = 0; b < 2; ++b) {
            const int off = (nt * 16 + m) * 64 + b * 32 + g * 8;
            Bc[nt][b] = *(const bf16x8*)&kvT[kvb + off];
            Bs[nt][b] = *(const bf16x8*)&kvT[kvb + 4096 + off];
        }

    const int sA = chunk * 256 + wv * 16 + m;   // this lane's A row, tile it=0
    f32x4 qb[4], qn[4];
    #pragma unroll
    for (int p = 0; p < 4; ++p)
        qb[p] = *(const f32x4*)&q[qbase + (size_t)sA * DH + (p >> 1) * 32 + g * 8 + (p & 1) * 4];

    for (int it = 0; it < 4; ++it) {
        const int srow = sA + it * 64;
        if (it < 3) {
            #pragma unroll
            for (int p = 0; p < 4; ++p)
                qn[p] = *(const f32x4*)&q[qbase + (size_t)(srow + 64) * DH + (p >> 1) * 32 + g * 8 + (p & 1) * 4];
        }
        float sn, c;
        __sincosf(ANG * (float)srow, &sn, &c);
        union { bf16x8 v; __bf16 e[8]; } Ac[2], As[2];
        #pragma unroll
        for (int p = 0; p < 4; ++p) {
            #pragma unroll
            for (int i = 0; i < 4; ++i) {
                const float qf = featf(qb[p][i]);
                Ac[p >> 1].e[(p & 1) * 4 + i] = (__bf16)(qf * c);
                As[p >> 1].e[(p & 1) * 4 + i] = (__bf16)(qf * sn);
            }
        }
        f32x4 acc[4] = {};
        #pragma unroll
        for (int nt = 0; nt < 4; ++nt) {
            acc[nt] = __builtin_amdgcn_mfma_f32_16x16x32_bf16(Ac[0].v, Bc[nt][0], acc[nt], 0, 0, 0);
            acc[nt] = __builtin_amdgcn_mfma_f32_16x16x32_bf16(Ac[1].v, Bc[nt][1], acc[nt], 0, 0, 0);
            acc[nt] = __builtin_amdgcn_mfma_f32_16x16x32_bf16(As[0].v, Bs[nt][0], acc[nt], 0, 0, 0);
            acc[nt] = __builtin_amdgcn_mfma_f32_16x16x32_bf16(As[1].v, Bs[nt][1], acc[nt], 0, 0, 0);
        }
        const int s0 = chunk * 256 + (it * 4 + wv) * 16;
        #pragma unroll
        for (int r = 0; r < 4; ++r) {
            const size_t ob = ((size_t)bh * SLEN + s0 + g * 4 + r) * 64;
            #pragma unroll
            for (int nt = 0; nt < 4; ++nt)
                out[ob + nt * 16 + m] = acc[nt][r];
        }
        if (it < 3) {
            #pragma unroll
            for (int p = 0; p < 4; ++p) qb[p] = qn[p];
        }
    }
}

extern "C" void kernel_launch(void* const* d_in, const int* in_sizes, int n_in,
                              void* d_out, int out_size, void* d_ws, size_t ws_size,
                              hipStream_t stream) {
    const float* q = (const float*)d_in[0];
    const float* k = (const float*)d_in[1];
    const float* v = (const float*)d_in[2];
    float* out  = (float*)d_out;
    float* part = (float*)d_ws;                                   // 16 MB
    short* kvT  = (short*)((char*)d_ws + (size_t)BHN * CH * 8192 * 4); // +1 MB

    hipLaunchKernelGGL(kv_partial, dim3(BHN * CH), dim3(256), 0, stream, k, v, part);
    hipLaunchKernelGGL(kv_reduce,  dim3(BHN * 4),  dim3(256), 0, stream, part, kvT);
    hipLaunchKernelGGL(out_kernel, dim3(BHN * 16), dim3(256), 0, stream, q, kvT, out);
}

// Round 3
// 66.829 us; speedup vs baseline: 4.7700x; 1.1132x over previous
//
#include <hip/hip_runtime.h>
#include <math.h>

#define SLEN 4096
#define DH   64
#define BHN  64
#define CH   16
#define ROWSPER 256   // SLEN / CH
#define NT   4        // 64-row tiles per block
#define SPAD 72       // LDS row stride in shorts

typedef float  f32x4  __attribute__((ext_vector_type(4)));
typedef short  s16x4  __attribute__((ext_vector_type(4)));
typedef __bf16 bf16x8 __attribute__((ext_vector_type(8)));

static constexpr float ANG  = 1.5707963267948966f / 4096.0f; // (pi/2)/S
static constexpr float C1   = 0.9999999264657180f;   // cos(ANG)
static constexpr float S1   = 3.8349518757139556e-4f;// sin(ANG)
static constexpr float ROTC = 0.9996988186962042f;   // cos(64*ANG) = cos(pi/128)
static constexpr float ROTS = 0.024541228522912288f; // sin(64*ANG)

static __device__ __forceinline__ float featf(float x) {
    return x < 0.f ? __expf(x) : x + 1.f;
}
static __device__ __forceinline__ void pack2(short* p, float a, float b) {
    union { __bf16 h[2]; unsigned u; } uu;
    uu.h[0] = (__bf16)a; uu.h[1] = (__bf16)b;
    *(unsigned*)p = uu.u;
}
static __device__ __forceinline__ float b2f(short s) {
    unsigned u = ((unsigned)(unsigned short)s) << 16;
    float f; __builtin_memcpy(&f, &u, 4); return f;
}
static __device__ __forceinline__ short f2b(float f) {
    __bf16 h = (__bf16)f; short s; __builtin_memcpy(&s, &h, 2); return s;
}

// ---------------- Kernel 1: partial KV aggregation (MFMA, pipelined) --------
// part layout: [bh*CH + ch][2(cos,sin)][64 d][64 e] bf16
__global__ __launch_bounds__(256) void kv_partial(const float* __restrict__ k,
                                                  const float* __restrict__ v,
                                                  short* __restrict__ part)
{
    __shared__ short kcT[64 * SPAD];  // [d][s] bf16 bits, s-blocks XOR-swizzled
    __shared__ short ksT[64 * SPAD];
    __shared__ short vT [64 * SPAD];  // [e][s]

    const int bx = blockIdx.x;
    const int bh = bx >> 4, ch = bx & 15;
    const size_t base = (size_t)bh * SLEN * DH;
    const int t  = threadIdx.x;
    const int wv = t >> 6;
    const int ln = t & 63;
    const int m  = ln & 15;
    const int g  = ln >> 4;
    const int d0 = (t & 15) * 4;    // staging: 4 feature cols
    const int sg = t >> 4;          // staging: row-pair index 0..15
    const int srow_base = ch * ROWSPER;

    // angle state: (cos,sin) for rows sl(it)=it*32+sg*2 and sl+1; rotate per tile
    float cA[2], sA[2], cB[2], sB[2];
    #pragma unroll
    for (int it = 0; it < 2; ++it) {
        float sn, cs;
        __sincosf(ANG * (float)(srow_base + it * 32 + sg * 2), &sn, &cs);
        cA[it] = cs;            sA[it] = sn;
        cB[it] = cs * C1 - sn * S1;
        sB[it] = sn * C1 + cs * S1;
    }

    f32x4 aC[4] = {}; f32x4 aS[4] = {};
    f32x4 K0[2][2], K1[2][2], V0[2][2], V1[2][2]; // [buf][it]

#define LOADT(BUF, TILE)                                                      \
    _Pragma("unroll")                                                         \
    for (int it = 0; it < 2; ++it) {                                          \
        const size_t r = base + (size_t)(srow_base + (TILE) * 64 + it * 32 + sg * 2) * DH + d0; \
        K0[BUF][it] = *(const f32x4*)&k[r];                                   \
        K1[BUF][it] = *(const f32x4*)&k[r + DH];                              \
        V0[BUF][it] = *(const f32x4*)&v[r];                                   \
        V1[BUF][it] = *(const f32x4*)&v[r + DH];                              \
    }

    LOADT(0, 0);

    #pragma unroll
    for (int tile = 0; tile < NT; ++tile) {
        const int buf = tile & 1;
        if (tile) __syncthreads();          // prev MFMA reads done before overwrite
        #pragma unroll
        for (int it = 0; it < 2; ++it) {
            const int sl = it * 32 + sg * 2;
            #pragma unroll
            for (int i = 0; i < 4; ++i) {
                const int d  = d0 + i;
                const float kf0 = featf(K0[buf][it][i]);
                const float kf1 = featf(K1[buf][it][i]);
                const int pos = ((((sl >> 3) ^ ((d >> 2) & 7)) << 3) | (sl & 7));
                const int ro  = d * SPAD + pos;
                pack2(&kcT[ro], kf0 * cA[it], kf1 * cB[it]);
                pack2(&ksT[ro], kf0 * sA[it], kf1 * sB[it]);
                pack2(&vT [ro], V0[buf][it][i], V1[buf][it][i]);
            }
        }
        __syncthreads();
        if (tile + 1 < NT) { LOADT(buf ^ 1, tile + 1); }
        // rotate angles for next tile (+64 rows)
        #pragma unroll
        for (int it = 0; it < 2; ++it) {
            float c = cA[it], s = sA[it];
            cA[it] = c * ROTC - s * ROTS; sA[it] = s * ROTC + c * ROTS;
            c = cB[it]; s = sB[it];
            cB[it] = c * ROTC - s * ROTS; sB[it] = s * ROTC + c * ROTS;
        }
        // MFMA over the staged 64-row tile
        #pragma unroll
        for (int b = 0; b < 2; ++b) {
            const int s3 = b * 4 + g;            // s-block index (so>>3)
            const int dA = wv * 16 + m;
            const int oA = dA * SPAD + ((s3 ^ ((dA >> 2) & 7)) << 3);
            const bf16x8 Ac = *(const bf16x8*)&kcT[oA];
            const bf16x8 As = *(const bf16x8*)&ksT[oA];
            #pragma unroll
            for (int nt = 0; nt < 4; ++nt) {
                const int dB = nt * 16 + m;
                const int oB = dB * SPAD + ((s3 ^ ((dB >> 2) & 7)) << 3);
                const bf16x8 Bv = *(const bf16x8*)&vT[oB];
                aC[nt] = __builtin_amdgcn_mfma_f32_16x16x32_bf16(Ac, Bv, aC[nt], 0, 0, 0);
                aS[nt] = __builtin_amdgcn_mfma_f32_16x16x32_bf16(As, Bv, aS[nt], 0, 0, 0);
            }
        }
    }
#undef LOADT

    // C/D: col = lane&15, row = 4*(lane>>4)+reg
    const size_t pb = (size_t)bx * 8192;
    #pragma unroll
    for (int nt = 0; nt < 4; ++nt) {
        #pragma unroll
        for (int r = 0; r < 4; ++r) {
            const int rowb = (wv * 16 + g * 4 + r) * 64 + nt * 16 + m;
            part[pb        + rowb] = f2b(aC[nt][r]);
            part[pb + 4096 + rowb] = f2b(aS[nt][r]);
        }
    }
}

// ---------------- Kernel 2: reduce chunks, emit bf16 KV^T -------------------
// kvT layout: [bh][2(cos,sin)][64 e][64 d] bf16
__global__ __launch_bounds__(256) void kv_reduce(const short* __restrict__ part,
                                                 short* __restrict__ kvT)
{
    const int bx = blockIdx.x;          // 512 blocks: bh = bx>>3, seg = bx&7
    const int bh = bx >> 3, seg = bx & 7;
    const size_t pbase = (size_t)bh * CH * 8192;
    const int j0 = seg * 1024 + threadIdx.x * 4;   // 4 consecutive j per thread
    float acc[4] = {};
    #pragma unroll
    for (int c = 0; c < CH; ++c) {
        const s16x4 sv = *(const s16x4*)&part[pbase + (size_t)c * 8192 + j0];
        #pragma unroll
        for (int i = 0; i < 4; ++i) acc[i] += b2f(sv[i]);
    }
    const int cs = j0 >> 12;
    const int d  = (j0 >> 6) & 63;
    const int e0 = j0 & 63;
    #pragma unroll
    for (int i = 0; i < 4; ++i)
        kvT[(size_t)bh * 8192 + cs * 4096 + (e0 + i) * 64 + d] = f2b(acc[i]);
}

// ---------------- Kernel 3: out = Qc*KVc + Qs*KVs (MFMA) --------------------
__global__ __launch_bounds__(256) void out_kernel(const float* __restrict__ q,
                                                  const short* __restrict__ kvT,
                                                  float* __restrict__ out)
{
    const int bx = blockIdx.x;
    const int bh = bx >> 4, chunk = bx & 15;
    const int t = threadIdx.x;
    const int wv = t >> 6, ln = t & 63, m = ln & 15, g = ln >> 4;
    const size_t qbase = (size_t)bh * SLEN * DH;
    const size_t kvb   = (size_t)bh * 8192;

    bf16x8 Bc[4][2], Bs[4][2];
    #pragma unroll
    for (int nt = 0; nt < 4; ++nt)
        #pragma unroll
        for (int b = 0; b < 2; ++b) {
            const int off = (nt * 16 + m) * 64 + b * 32 + g * 8;
            Bc[nt][b] = *(const bf16x8*)&kvT[kvb + off];
            Bs[nt][b] = *(const bf16x8*)&kvT[kvb + 4096 + off];
        }

    const int sA = chunk * 256 + wv * 16 + m;
    f32x4 qb[4], qn[4];
    #pragma unroll
    for (int p = 0; p < 4; ++p)
        qb[p] = *(const f32x4*)&q[qbase + (size_t)sA * DH + (p >> 1) * 32 + g * 8 + (p & 1) * 4];

    for (int it = 0; it < 4; ++it) {
        const int srow = sA + it * 64;
        if (it < 3) {
            #pragma unroll
            for (int p = 0; p < 4; ++p)
                qn[p] = *(const f32x4*)&q[qbase + (size_t)(srow + 64) * DH + (p >> 1) * 32 + g * 8 + (p & 1) * 4];
        }
        float sn, c;
        __sincosf(ANG * (float)srow, &sn, &c);
        union { bf16x8 v; __bf16 e[8]; } Ac[2], As[2];
        #pragma unroll
        for (int p = 0; p < 4; ++p) {
            #pragma unroll
            for (int i = 0; i < 4; ++i) {
                const float qf = featf(qb[p][i]);
                Ac[p >> 1].e[(p & 1) * 4 + i] = (__bf16)(qf * c);
                As[p >> 1].e[(p & 1) * 4 + i] = (__bf16)(qf * sn);
            }
        }
        f32x4 acc[4] = {};
        #pragma unroll
        for (int nt = 0; nt < 4; ++nt) {
            acc[nt] = __builtin_amdgcn_mfma_f32_16x16x32_bf16(Ac[0].v, Bc[nt][0], acc[nt], 0, 0, 0);
            acc[nt] = __builtin_amdgcn_mfma_f32_16x16x32_bf16(Ac[1].v, Bc[nt][1], acc[nt], 0, 0, 0);
            acc[nt] = __builtin_amdgcn_mfma_f32_16x16x32_bf16(As[0].v, Bs[nt][0], acc[nt], 0, 0, 0);
            acc[nt] = __builtin_amdgcn_mfma_f32_16x16x32_bf16(As[1].v, Bs[nt][1], acc[nt], 0, 0, 0);
        }
        const int s0 = chunk * 256 + (it * 4 + wv) * 16;
        #pragma unroll
        for (int r = 0; r < 4; ++r) {
            const size_t ob = ((size_t)bh * SLEN + s0 + g * 4 + r) * 64;
            #pragma unroll
            for (int nt = 0; nt < 4; ++nt)
                out[ob + nt * 16 + m] = acc[nt][r];
        }
        if (it < 3) {
            #pragma unroll
            for (int p = 0; p < 4; ++p) qb[p] = qn[p];
        }
    }
}

extern "C" void kernel_launch(void* const* d_in, const int* in_sizes, int n_in,
                              void* d_out, int out_size, void* d_ws, size_t ws_size,
                              hipStream_t stream) {
    const float* q = (const float*)d_in[0];
    const float* k = (const float*)d_in[1];
    const float* v = (const float*)d_in[2];
    float* out  = (float*)d_out;
    short* part = (short*)d_ws;                                        // 16 MB
    short* kvT  = (short*)((char*)d_ws + (size_t)BHN * CH * 8192 * 2); // +1 MB

    hipLaunchKernelGGL(kv_partial, dim3(BHN * CH), dim3(256), 0, stream, k, v, part);
    hipLaunchKernelGGL(kv_reduce,  dim3(BHN * 8),  dim3(256), 0, stream, part, kvT);
    hipLaunchKernelGGL(out_kernel, dim3(BHN * 16), dim3(256), 0, stream, q, kvT, out);
}

// Round 4
// 66.319 us; speedup vs baseline: 4.8067x; 1.0077x over previous
//
#include <hip/hip_runtime.h>
#include <math.h>

#define SLEN 4096
#define DH   64
#define BHN  64
#define CH   16
#define ROWSPER 256   // SLEN / CH

typedef float  f32x4   __attribute__((ext_vector_type(4)));
typedef float  f32x16  __attribute__((ext_vector_type(16)));
typedef short  s16x4   __attribute__((ext_vector_type(4)));
typedef __bf16 bf16x8  __attribute__((ext_vector_type(8)));

static constexpr float ANG = 3.8349519697141029e-4f;   // (pi/2)/4096

static __device__ __forceinline__ float featf(float x) {
    return x < 0.f ? __expf(x) : x + 1.f;   // elu+1 feature map
}
static __device__ __forceinline__ float b2f(short s) {
    unsigned u = ((unsigned)(unsigned short)s) << 16;
    float f; __builtin_memcpy(&f, &u, 4); return f;
}
static __device__ __forceinline__ short f2b(float f) {
    __bf16 h = (__bf16)f; short s; __builtin_memcpy(&s, &h, 2); return s;
}

// ---------------- Kernel 1: partial KV aggregation ---------------------------
// Register-direct MFMA: no LDS, no barriers. Each wave owns a (d-half, e-half)
// 32x32 quadrant; lane (m = l&31, g = l>>5) loads k[s][dcol] / v[s][ecol] for
// s = step*16 + g*8 + j, builds bf16 fragments in registers, and accumulates
// with v_mfma_f32_32x32x16_bf16.  part: [bh*CH+ch][2(cos,sin)][64 d][64 e] bf16
__global__ __launch_bounds__(256) void kv_partial(const float* __restrict__ k,
                                                  const float* __restrict__ v,
                                                  short* __restrict__ part)
{
    // cos/sin(j*ANG), j=0..7 (compile-time folded under full unroll)
    static constexpr float CJ[8] = {
        1.0f, 0.999999926470f, 0.9999997058633f, 0.9999993381923f,
        0.9999988234532f, 0.9999981616455f, 0.9999973527695f, 0.9999963968250f};
    static constexpr float SJ[8] = {
        0.0f, 3.83495188e-4f, 7.66990319e-4f, 1.15048534e-3f,
        1.53398019e-3f, 1.91747481e-3f, 2.30096915e-3f, 2.68446316e-3f};
    static constexpr float RC16 = 0.99998117528260111f;   // cos(pi/512)
    static constexpr float RS16 = 6.1358846491544753e-3f; // sin(pi/512)

    const int bx = blockIdx.x;
    const int bh = bx >> 4, ch = bx & 15;
    const size_t base = (size_t)bh * SLEN * DH;
    const int t  = threadIdx.x;
    const int w  = t >> 6;            // wave 0..3
    const int l  = t & 63;
    const int m  = l & 31;
    const int g  = l >> 5;            // 0/1
    const int dh = w >> 1;            // d half
    const int eh = w & 1;             // e half
    const int dcol = dh * 32 + m;
    const int ecol = eh * 32 + m;
    const int s_base = ch * ROWSPER;

    // base angle for this lane's row group (s = s_base + g*8), rotated per step
    float c0, s0;
    __sincosf(ANG * (float)(s_base + g * 8), &s0, &c0);

    f32x16 accC = {}; f32x16 accS = {};
    float kr[2][8], vr[2][8];         // double-buffered raw loads (static idx)

#define LOADS(BUF, STEP) {                                                     \
        const size_t r0 = base + (size_t)(s_base + (STEP) * 16 + g * 8) * DH;  \
        _Pragma("unroll")                                                      \
        for (int j = 0; j < 8; ++j) {                                          \
            kr[BUF][j] = k[r0 + (size_t)j * DH + dcol];                        \
            vr[BUF][j] = v[r0 + (size_t)j * DH + ecol];                        \
        } }

    LOADS(0, 0)
    #pragma unroll
    for (int step = 0; step < 16; ++step) {
        const int buf = step & 1;
        if (step + 1 < 16) LOADS(buf ^ 1, step + 1)
        union { bf16x8 v; __bf16 e[8]; } Ac, As, Bv;
        #pragma unroll
        for (int j = 0; j < 8; ++j) {
            const float kf = featf(kr[buf][j]);
            const float p  = kf * c0;
            const float q  = kf * s0;
            Ac.e[j] = (__bf16)(p * CJ[j] - q * SJ[j]);   // kf*cos(ANG*(s0g+j))
            As.e[j] = (__bf16)(q * CJ[j] + p * SJ[j]);   // kf*sin
            Bv.e[j] = (__bf16)vr[buf][j];
        }
        accC = __builtin_amdgcn_mfma_f32_32x32x16_bf16(Ac.v, Bv.v, accC, 0, 0, 0);
        accS = __builtin_amdgcn_mfma_f32_32x32x16_bf16(As.v, Bv.v, accS, 0, 0, 0);
        const float cn = c0 * RC16 - s0 * RS16;          // advance 16 rows
        s0 = s0 * RC16 + c0 * RS16;
        c0 = cn;
    }
#undef LOADS

    // C/D 32x32: col = lane&31 (e), row = (reg&3) + 8*(reg>>2) + 4*(lane>>5) (d)
    const size_t pb = (size_t)bx * 8192;
    #pragma unroll
    for (int r = 0; r < 16; ++r) {
        const int drow = dh * 32 + (r & 3) + 8 * (r >> 2) + 4 * g;
        const size_t o = pb + (size_t)drow * 64 + ecol;
        part[o]        = f2b(accC[r]);
        part[o + 4096] = f2b(accS[r]);
    }
}

// ---------------- Kernel 2: reduce chunks, emit bf16 KV^T -------------------
// kvT layout: [bh][2(cos,sin)][64 e][64 d] bf16
__global__ __launch_bounds__(256) void kv_reduce(const short* __restrict__ part,
                                                 short* __restrict__ kvT)
{
    const int bx = blockIdx.x;          // 512 blocks: bh = bx>>3, seg = bx&7
    const int bh = bx >> 3, seg = bx & 7;
    const size_t pbase = (size_t)bh * CH * 8192;
    const int j0 = seg * 1024 + threadIdx.x * 4;
    float acc[4] = {};
    #pragma unroll
    for (int c = 0; c < CH; ++c) {
        const s16x4 sv = *(const s16x4*)&part[pbase + (size_t)c * 8192 + j0];
        #pragma unroll
        for (int i = 0; i < 4; ++i) acc[i] += b2f(sv[i]);
    }
    const int cs = j0 >> 12;
    const int d  = (j0 >> 6) & 63;
    const int e0 = j0 & 63;
    #pragma unroll
    for (int i = 0; i < 4; ++i)
        kvT[(size_t)bh * 8192 + cs * 4096 + (e0 + i) * 64 + d] = f2b(acc[i]);
}

// ---------------- Kernel 3: out = Qc*KVc + Qs*KVs (MFMA) --------------------
__global__ __launch_bounds__(256) void out_kernel(const float* __restrict__ q,
                                                  const short* __restrict__ kvT,
                                                  float* __restrict__ out)
{
    const int bx = blockIdx.x;
    const int bh = bx >> 4, chunk = bx & 15;
    const int t = threadIdx.x;
    const int wv = t >> 6, ln = t & 63, m = ln & 15, g = ln >> 4;
    const size_t qbase = (size_t)bh * SLEN * DH;
    const size_t kvb   = (size_t)bh * 8192;

    bf16x8 Bc[4][2], Bs[4][2];
    #pragma unroll
    for (int nt = 0; nt < 4; ++nt)
        #pragma unroll
        for (int b = 0; b < 2; ++b) {
            const int off = (nt * 16 + m) * 64 + b * 32 + g * 8;
            Bc[nt][b] = *(const bf16x8*)&kvT[kvb + off];
            Bs[nt][b] = *(const bf16x8*)&kvT[kvb + 4096 + off];
        }

    const int sA = chunk * 256 + wv * 16 + m;
    f32x4 qb[4], qn[4];
    #pragma unroll
    for (int p = 0; p < 4; ++p)
        qb[p] = *(const f32x4*)&q[qbase + (size_t)sA * DH + (p >> 1) * 32 + g * 8 + (p & 1) * 4];

    for (int it = 0; it < 4; ++it) {
        const int srow = sA + it * 64;
        if (it < 3) {
            #pragma unroll
            for (int p = 0; p < 4; ++p)
                qn[p] = *(const f32x4*)&q[qbase + (size_t)(srow + 64) * DH + (p >> 1) * 32 + g * 8 + (p & 1) * 4];
        }
        float sn, c;
        __sincosf(ANG * (float)srow, &sn, &c);
        union { bf16x8 v; __bf16 e[8]; } Ac[2], As[2];
        #pragma unroll
        for (int p = 0; p < 4; ++p) {
            #pragma unroll
            for (int i = 0; i < 4; ++i) {
                const float qf = featf(qb[p][i]);
                Ac[p >> 1].e[(p & 1) * 4 + i] = (__bf16)(qf * c);
                As[p >> 1].e[(p & 1) * 4 + i] = (__bf16)(qf * sn);
            }
        }
        f32x4 acc[4] = {};
        #pragma unroll
        for (int nt = 0; nt < 4; ++nt) {
            acc[nt] = __builtin_amdgcn_mfma_f32_16x16x32_bf16(Ac[0].v, Bc[nt][0], acc[nt], 0, 0, 0);
            acc[nt] = __builtin_amdgcn_mfma_f32_16x16x32_bf16(Ac[1].v, Bc[nt][1], acc[nt], 0, 0, 0);
            acc[nt] = __builtin_amdgcn_mfma_f32_16x16x32_bf16(As[0].v, Bs[nt][0], acc[nt], 0, 0, 0);
            acc[nt] = __builtin_amdgcn_mfma_f32_16x16x32_bf16(As[1].v, Bs[nt][1], acc[nt], 0, 0, 0);
        }
        const int s0 = chunk * 256 + (it * 4 + wv) * 16;
        #pragma unroll
        for (int r = 0; r < 4; ++r) {
            const size_t ob = ((size_t)bh * SLEN + s0 + g * 4 + r) * 64;
            #pragma unroll
            for (int nt = 0; nt < 4; ++nt)
                out[ob + nt * 16 + m] = acc[nt][r];
        }
        if (it < 3) {
            #pragma unroll
            for (int p = 0; p < 4; ++p) qb[p] = qn[p];
        }
    }
}

extern "C" void kernel_launch(void* const* d_in, const int* in_sizes, int n_in,
                              void* d_out, int out_size, void* d_ws, size_t ws_size,
                              hipStream_t stream) {
    const float* q = (const float*)d_in[0];
    const float* k = (const float*)d_in[1];
    const float* v = (const float*)d_in[2];
    float* out  = (float*)d_out;
    short* part = (short*)d_ws;                                        // 16 MB
    short* kvT  = (short*)((char*)d_ws + (size_t)BHN * CH * 8192 * 2); // +1 MB

    hipLaunchKernelGGL(kv_partial, dim3(BHN * CH), dim3(256), 0, stream, k, v, part);
    hipLaunchKernelGGL(kv_reduce,  dim3(BHN * 8),  dim3(256), 0, stream, part, kvT);
    hipLaunchKernelGGL(out_kernel, dim3(BHN * 16), dim3(256), 0, stream, q, kvT, out);
}